// Round 1
// 4177.222 us; speedup vs baseline: 1.0706x; 1.0706x over previous
//
#include <hip/hip_runtime.h>
#include <cstdint>
#include <cstddef>

#define BATCH 256
#define SEQ   512
#define DIM   1024
#define HID   2048
#define NOUT  32

// ---- new GEMM geometry: 256x256 tile, BK=64, K' = 3*1024 = 3072 ----
#define BM 256
#define BN 256
#define BK 64
#define KT_PER_SEG 16                 // 1024 / 64
#define KSTEPS 48                     // 3 segments (AhBh, AhBl, AlBh)
#define TM_TILES 512                  // 131072 / 256
#define TN_TILES 8                    // 2048 / 256
#define TILE_SHORTS (BM * BK)         // 16384 shorts = 32 KB per tile

typedef __attribute__((ext_vector_type(8))) short  short8;
typedef __attribute__((ext_vector_type(4))) float  f32x4;

__device__ __forceinline__ ushort f2bf(float v) {
    uint u = __builtin_bit_cast(uint, v);
    u = u + 0x7FFFu + ((u >> 16) & 1u);     // round-to-nearest-even
    return (ushort)(u >> 16);
}
__device__ __forceinline__ float bf2f(ushort h) {
    uint u = ((uint)h) << 16;
    return __builtin_bit_cast(float, u);
}

__device__ __forceinline__ void gload16(const ushort* g, ushort* l) {
    __builtin_amdgcn_global_load_lds(
        (const __attribute__((address_space(1))) uint32_t*)(g),
        (__attribute__((address_space(3))) uint32_t*)(l),
        16, 0, 0);
}

// branch-free tanh: exact identity, __expf err ~1e-6 rel
__device__ __forceinline__ float fast_tanh(float x) {
    float e = __expf(2.0f * x);
    return 1.0f - 2.0f / (e + 1.0f);
}

// ---------------------------------------------------------------------------
// prep_a: x fp32 [131072][1024] -> A'h / A'l bf16, tiled [tm][kt][kc8][row256][j8]
// (tile image == LDS image so GEMM staging is a pure linear copy)
// ---------------------------------------------------------------------------
__global__ __launch_bounds__(256) void prep_a(const float* __restrict__ x,
                                              ushort* __restrict__ Ah,
                                              ushort* __restrict__ Al)
{
    __shared__ alignas(16) ushort hi[TILE_SHORTS];
    __shared__ alignas(16) ushort lo[TILE_SHORTS];
    const int tm = blockIdx.x;          // 0..511
    const int kt = blockIdx.y;          // 0..15
    const int t  = threadIdx.x;         // 0..255

#pragma unroll
    for (int p = 0; p < 4; ++p) {
        const int row  = p * 64 + (t >> 2);        // 0..255
        const int part = t & 3;                    // 16 k each
        const float* src = x + (size_t)(tm * 256 + row) * DIM + kt * 64 + part * 16;
        float4 v0 = *(const float4*)(src);
        float4 v1 = *(const float4*)(src + 4);
        float4 v2 = *(const float4*)(src + 8);
        float4 v3 = *(const float4*)(src + 12);
        float av[16] = {v0.x, v0.y, v0.z, v0.w, v1.x, v1.y, v1.z, v1.w,
                        v2.x, v2.y, v2.z, v2.w, v3.x, v3.y, v3.z, v3.w};
#pragma unroll
        for (int g = 0; g < 2; ++g) {
            short8 hs, ls;
#pragma unroll
            for (int i = 0; i < 8; ++i) {
                float vv = av[g * 8 + i];
                ushort hh = f2bf(vv);
                hs[i] = (short)hh;
                ls[i] = (short)f2bf(vv - bf2f(hh));
            }
            const int kc = part * 2 + g;           // 0..7
            *(short8*)&hi[(kc * 256 + row) * 8] = hs;
            *(short8*)&lo[(kc * 256 + row) * 8] = ls;
        }
    }
    __syncthreads();
    const size_t tbase = ((size_t)tm * KT_PER_SEG + kt) * TILE_SHORTS;
#pragma unroll
    for (int i = 0; i < 8; ++i) {
        const int idx = i * 2048 + t * 8;
        *(short8*)(Ah + tbase + idx) = *(const short8*)(hi + idx);
        *(short8*)(Al + tbase + idx) = *(const short8*)(lo + idx);
    }
}

// ---------------------------------------------------------------------------
// prep_b: W1[:1024] fp32 [K][N] -> B'h / B'l bf16 (B^T), tiled like A'
// ---------------------------------------------------------------------------
__global__ __launch_bounds__(256) void prep_b(const float* __restrict__ W1,
                                              ushort* __restrict__ Bh,
                                              ushort* __restrict__ Bl)
{
    __shared__ alignas(16) ushort hi[TILE_SHORTS];
    __shared__ alignas(16) ushort lo[TILE_SHORTS];
    const int tn = blockIdx.x;          // 0..7
    const int kt = blockIdx.y;          // 0..15
    const int t  = threadIdx.x;

#pragma unroll
    for (int p = 0; p < 16; ++p) {
        const int krow = p * 4 + (t >> 6);         // 0..63
        const int n4   = (t & 63) * 4;             // 0..252
        float4 v = *(const float4*)&W1[(size_t)(kt * 64 + krow) * HID + tn * 256 + n4];
        const int kc = krow >> 3, j = krow & 7;
        float vv[4] = {v.x, v.y, v.z, v.w};
#pragma unroll
        for (int q = 0; q < 4; ++q) {
            ushort hh = f2bf(vv[q]);
            hi[(kc * 256 + n4 + q) * 8 + j] = hh;
            lo[(kc * 256 + n4 + q) * 8 + j] = f2bf(vv[q] - bf2f(hh));
        }
    }
    __syncthreads();
    const size_t tbase = ((size_t)tn * KT_PER_SEG + kt) * TILE_SHORTS;
#pragma unroll
    for (int i = 0; i < 8; ++i) {
        const int idx = i * 2048 + t * 8;
        *(short8*)(Bh + tbase + idx) = *(const short8*)(hi + idx);
        *(short8*)(Bl + tbase + idx) = *(const short8*)(lo + idx);
    }
}

// ---------------------------------------------------------------------------
// gemm256: G = A' @ B'^T + b1, K'=3072 (3-product bf16 split via K-concat).
// 256x256 tile, 8 waves (2Mx4N), BK=64, double-buffered gload_lds,
// counted vmcnt(8) pipeline (2-deep), setprio around MFMA clusters.
// seg0: (Ah,Bh)  seg1: (Ah,Bl)  seg2: (Al,Bh)
// ---------------------------------------------------------------------------
__global__ __launch_bounds__(512, 2) void gemm256(const ushort* __restrict__ Ah,
                                                  const ushort* __restrict__ Alo,
                                                  const ushort* __restrict__ Bh,
                                                  const ushort* __restrict__ Blo,
                                                  const float*  __restrict__ b1,
                                                  float* __restrict__ G)
{
    __shared__ alignas(16) ushort lds[2][2][TILE_SHORTS];   // 2 buf x {A,B} = 128 KiB

    const int tid  = threadIdx.x;
    const int lane = tid & 63;
    const int wave = tid >> 6;
    const int fr = lane & 15;
    const int fq = lane >> 4;
    const int wm = (wave >> 2) * 128;
    const int wn = (wave & 3) * 64;

    // XCD-chunked swizzle (nwg=4096, %8==0), m-major / n-inner:
    // each XCD gets 64 consecutive m-tiles x all 8 n-tiles -> A-panel L2-hot.
    const int cpx = (TM_TILES * TN_TILES) >> 3;   // 512
    const int wg  = blockIdx.x;
    const int swz = (wg & 7) * cpx + (wg >> 3);
    const int tm  = swz >> 3;
    const int tn  = swz & 7;

    auto stage = [&](int buf, int ks) {
        const int seg = ks >> 4, kt = ks & 15;
        const ushort* at = ((seg == 2) ? Alo : Ah) + ((size_t)tm * KT_PER_SEG + kt) * TILE_SHORTS;
        const ushort* bt = ((seg == 1) ? Blo : Bh) + ((size_t)tn * KT_PER_SEG + kt) * TILE_SHORTS;
        ushort* la = &lds[buf][0][0];
        ushort* lb = &lds[buf][1][0];
#pragma unroll
        for (int i = 0; i < 4; ++i)
            gload16(at + i * 4096 + tid * 8, la + i * 4096 + tid * 8);
#pragma unroll
        for (int i = 0; i < 4; ++i)
            gload16(bt + i * 4096 + tid * 8, lb + i * 4096 + tid * 8);
    };

    f32x4 acc[8][4];
#pragma unroll
    for (int i = 0; i < 8; ++i)
#pragma unroll
        for (int j = 0; j < 4; ++j) {
            f32x4 z = {0.f, 0.f, 0.f, 0.f};
            acc[i][j] = z;
        }

    // prologue: 2-deep prefetch, 16 loads in flight; wait buf0's 8
    stage(0, 0);
    stage(1, 1);
    asm volatile("s_waitcnt vmcnt(8)" ::: "memory");
    __builtin_amdgcn_s_barrier();

    for (int ks = 0; ks < KSTEPS; ++ks) {
        const int cur = ks & 1;
        const ushort* LA = &lds[cur][0][0];
        const ushort* LB = &lds[cur][1][0];
#pragma unroll
        for (int kk = 0; kk < 2; ++kk) {
            const int kc = kk * 4 + fq;
            short8 a[8], b[4];
#pragma unroll
            for (int mt = 0; mt < 8; ++mt)
                a[mt] = *(const short8*)&LA[(kc * 256 + wm + mt * 16 + fr) * 8];
#pragma unroll
            for (int nt = 0; nt < 4; ++nt)
                b[nt] = *(const short8*)&LB[(kc * 256 + wn + nt * 16 + fr) * 8];
            __builtin_amdgcn_s_setprio(1);
#pragma unroll
            for (int mt = 0; mt < 8; ++mt)
#pragma unroll
                for (int nt = 0; nt < 4; ++nt)
                    acc[mt][nt] = __builtin_amdgcn_mfma_f32_16x16x32_bf16(a[mt], b[nt], acc[mt][nt], 0, 0, 0);
            __builtin_amdgcn_s_setprio(0);
        }
        asm volatile("" ::: "memory");
        __builtin_amdgcn_s_barrier();              // all waves done reading buf[cur]
        if (ks + 2 < KSTEPS) {
            stage(cur, ks + 2);                    // refill just-freed buffer
            asm volatile("s_waitcnt vmcnt(8)" ::: "memory");  // next buf's loads done
        } else {
            asm volatile("s_waitcnt vmcnt(0)" ::: "memory");  // tail drain
        }
        __builtin_amdgcn_s_barrier();
    }

    // epilogue: C/D layout col = lane&15, row = (lane>>4)*4 + reg
    const int m0 = tm * BM, n0 = tn * BN;
#pragma unroll
    for (int nt = 0; nt < 4; ++nt) {
        const int gn = n0 + wn + nt * 16 + fr;
        const float bias = b1[gn];
#pragma unroll
        for (int mt = 0; mt < 8; ++mt) {
            const int gm = m0 + wm + mt * 16 + fq * 4;
            float* out = G + (size_t)gm * HID + gn;
#pragma unroll
            for (int r = 0; r < 4; ++r)
                out[(size_t)r * HID] = acc[mt][nt][r] + bias;
        }
    }
}

// ---------------------------------------------------------------------------
// Fallback path (verbatim previous round, used only if ws too small)
// ---------------------------------------------------------------------------
__global__ __launch_bounds__(256) void split_w1t(const float* __restrict__ W1,
                                                 ushort* __restrict__ Bth,
                                                 ushort* __restrict__ Btl)
{
    __shared__ ushort th[32][33];
    __shared__ ushort tl[32][33];
    const int n0 = blockIdx.x * 32;
    const int k0 = blockIdx.y * 32;
    const int tx = threadIdx.x & 31;
    const int ty = threadIdx.x >> 5;
#pragma unroll
    for (int r = 0; r < 4; ++r) {
        int k = ty + r * 8;
        float v = W1[(size_t)(k0 + k) * HID + n0 + tx];
        ushort h = f2bf(v);
        th[k][tx] = h;
        tl[k][tx] = f2bf(v - bf2f(h));
    }
    __syncthreads();
#pragma unroll
    for (int r = 0; r < 4; ++r) {
        int n = ty + r * 8;
        Bth[(size_t)(n0 + n) * DIM + k0 + tx] = th[tx][n];
        Btl[(size_t)(n0 + n) * DIM + k0 + tx] = tl[tx][n];
    }
}

__global__ __launch_bounds__(256) void gemm_split(const float*  __restrict__ A,
                                                  const ushort* __restrict__ Bth,
                                                  const ushort* __restrict__ Btl,
                                                  const float*  __restrict__ b1,
                                                  float* __restrict__ G)
{
    __shared__ ushort Ahs[128][32];
    __shared__ ushort Als[128][32];
    __shared__ ushort Bhs[128][32];
    __shared__ ushort Bls[128][32];

    const int tid  = threadIdx.x;
    const int lane = tid & 63;
    const int wave = tid >> 6;
    const int n0 = blockIdx.x * 128;
    const int m0 = blockIdx.y * 128;
    const int wm = (wave & 1) * 64;
    const int wn = (wave >> 1) * 64;

    const int srow = tid >> 1;
    const int skc  = (tid & 1) * 16;
    const float*  aptr  = A   + (size_t)(m0 + srow) * DIM + skc;
    const ushort* bhptr = Bth + (size_t)(n0 + srow) * DIM + skc;
    const ushort* blptr = Btl + (size_t)(n0 + srow) * DIM + skc;

    const int fr = lane & 15;
    const int fq = lane >> 4;

    f32x4 acc[4][4];
#pragma unroll
    for (int i = 0; i < 4; ++i)
#pragma unroll
        for (int j = 0; j < 4; ++j) {
            f32x4 z = {0.f, 0.f, 0.f, 0.f};
            acc[i][j] = z;
        }

    for (int k0 = 0; k0 < DIM; k0 += 32) {
        float4 a0 = *(const float4*)(aptr + k0);
        float4 a1 = *(const float4*)(aptr + k0 + 4);
        float4 a2 = *(const float4*)(aptr + k0 + 8);
        float4 a3 = *(const float4*)(aptr + k0 + 12);
        short8 bh0 = *(const short8*)(bhptr + k0);
        short8 bh1 = *(const short8*)(bhptr + k0 + 8);
        short8 bl0 = *(const short8*)(blptr + k0);
        short8 bl1 = *(const short8*)(blptr + k0 + 8);

        __syncthreads();

        float av[16] = {a0.x, a0.y, a0.z, a0.w, a1.x, a1.y, a1.z, a1.w,
                        a2.x, a2.y, a2.z, a2.w, a3.x, a3.y, a3.z, a3.w};
        short8 h0, h1, l0, l1;
#pragma unroll
        for (int i = 0; i < 8; ++i) {
            ushort h = f2bf(av[i]);
            h0[i] = (short)h;
            l0[i] = (short)f2bf(av[i] - bf2f(h));
        }
#pragma unroll
        for (int i = 0; i < 8; ++i) {
            ushort h = f2bf(av[8 + i]);
            h1[i] = (short)h;
            l1[i] = (short)f2bf(av[8 + i] - bf2f(h));
        }
        *(short8*)&Ahs[srow][skc]     = h0;
        *(short8*)&Ahs[srow][skc + 8] = h1;
        *(short8*)&Als[srow][skc]     = l0;
        *(short8*)&Als[srow][skc + 8] = l1;
        *(short8*)&Bhs[srow][skc]     = bh0;
        *(short8*)&Bhs[srow][skc + 8] = bh1;
        *(short8*)&Bls[srow][skc]     = bl0;
        *(short8*)&Bls[srow][skc + 8] = bl1;

        __syncthreads();

        short8 afh[4], afl[4], bfh[4], bfl[4];
#pragma unroll
        for (int t = 0; t < 4; ++t) {
            afh[t] = *(const short8*)&Ahs[wm + t * 16 + fr][fq * 8];
            afl[t] = *(const short8*)&Als[wm + t * 16 + fr][fq * 8];
            bfh[t] = *(const short8*)&Bhs[wn + t * 16 + fr][fq * 8];
            bfl[t] = *(const short8*)&Bls[wn + t * 16 + fr][fq * 8];
        }
#pragma unroll
        for (int mt = 0; mt < 4; ++mt)
#pragma unroll
            for (int nt = 0; nt < 4; ++nt) {
                acc[mt][nt] = __builtin_amdgcn_mfma_f32_16x16x32_bf16(afh[mt], bfh[nt], acc[mt][nt], 0, 0, 0);
                acc[mt][nt] = __builtin_amdgcn_mfma_f32_16x16x32_bf16(afh[mt], bfl[nt], acc[mt][nt], 0, 0, 0);
                acc[mt][nt] = __builtin_amdgcn_mfma_f32_16x16x32_bf16(afl[mt], bfh[nt], acc[mt][nt], 0, 0, 0);
            }
    }

#pragma unroll
    for (int nt = 0; nt < 4; ++nt) {
        const int gn = n0 + wn + nt * 16 + fr;
        const float bias = b1[gn];
#pragma unroll
        for (int mt = 0; mt < 4; ++mt) {
            const int gmb = m0 + wm + mt * 16 + fq * 4;
            float* out = G + (size_t)gmb * HID + gn;
#pragma unroll
            for (int r = 0; r < 4; ++r)
                out[(size_t)r * HID] = acc[mt][nt][r] + bias;
        }
    }
}

// ---------------------------------------------------------------------------
// Kernel 2: sequential greedy decode (structure unchanged; tanhf -> fast_tanh)
// ---------------------------------------------------------------------------
__global__ __launch_bounds__(1024) void seq_scan(const float* __restrict__ G,
                                                 const float* __restrict__ W1,
                                                 const float* __restrict__ W2,
                                                 const float* __restrict__ b2,
                                                 float* __restrict__ out_logits,
                                                 float* __restrict__ out_preds)
{
    const int b   = blockIdx.x;
    const int t   = threadIdx.x;
    const int og  = t >> 8;
    const int j   = t & 255;
    const int o0  = og * 8;
    const int h0  = j * 8;

    __shared__ float hbuf[HID];
    __shared__ float partials[16][8];
    __shared__ int   pred_sh;

    float w2r[8][8];
#pragma unroll
    for (int i = 0; i < 8; ++i) {
        const float4* p4 = reinterpret_cast<const float4*>(&W2[(size_t)(h0 + i) * NOUT + o0]);
        float4 aa = p4[0], bbq = p4[1];
        w2r[i][0] = aa.x;  w2r[i][1] = aa.y;  w2r[i][2] = aa.z;  w2r[i][3] = aa.w;
        w2r[i][4] = bbq.x; w2r[i][5] = bbq.y; w2r[i][6] = bbq.z; w2r[i][7] = bbq.w;
    }

    int p = 0;
    const float* Gb = G + (size_t)b * SEQ * HID;
    float2 g = *reinterpret_cast<const float2*>(Gb + 2 * t);

    for (int step = 0; step < SEQ; ++step) {
        float2 u = *reinterpret_cast<const float2*>(&W1[(size_t)(DIM + p) * HID + 2 * t]);
        float hv0 = fast_tanh(g.x + u.x);
        float hv1 = fast_tanh(g.y + u.y);
        if (step + 1 < SEQ)
            g = *reinterpret_cast<const float2*>(Gb + (size_t)(step + 1) * HID + 2 * t);

        *reinterpret_cast<float2*>(&hbuf[2 * t]) = make_float2(hv0, hv1);
        __syncthreads();

        float4 ha = *reinterpret_cast<const float4*>(&hbuf[h0]);
        float4 hb = *reinterpret_cast<const float4*>(&hbuf[h0 + 4]);
        float hv[8] = {ha.x, ha.y, ha.z, ha.w, hb.x, hb.y, hb.z, hb.w};
        float acc[8];
#pragma unroll
        for (int c = 0; c < 8; ++c) acc[c] = 0.f;
#pragma unroll
        for (int i = 0; i < 8; ++i)
#pragma unroll
            for (int c = 0; c < 8; ++c)
                acc[c] = fmaf(hv[i], w2r[i][c], acc[c]);

#pragma unroll
        for (int off = 32; off; off >>= 1)
#pragma unroll
            for (int c = 0; c < 8; ++c)
                acc[c] += __shfl_xor(acc[c], off, 64);

        const int wave = t >> 6;
        const int lane = t & 63;
        if (lane == 0) {
#pragma unroll
            for (int c = 0; c < 8; ++c) partials[wave][c] = acc[c];
        }
        __syncthreads();

        if (t < 32) {
            const int o  = t;
            const int gq = o >> 3;
            const int c  = o & 7;
            float logit = b2[o] + partials[gq * 4 + 0][c] + partials[gq * 4 + 1][c]
                                + partials[gq * 4 + 2][c] + partials[gq * 4 + 3][c];
            out_logits[((size_t)b * SEQ + step) * NOUT + o] = logit;

            float v = logit; int idx = o;
#pragma unroll
            for (int off = 16; off; off >>= 1) {
                float ov = __shfl_xor(v, off, 32);
                int   oi = __shfl_xor(idx, off, 32);
                if (ov > v || (ov == v && oi < idx)) { v = ov; idx = oi; }
            }
            if (o == 0) {
                pred_sh = idx;
                out_preds[(size_t)b * SEQ + step] = (float)idx;
            }
        }
        __syncthreads();
        p = pred_sh;
    }
}

// ---------------------------------------------------------------------------
extern "C" void kernel_launch(void* const* d_in, const int* in_sizes, int n_in,
                              void* d_out, int out_size, void* d_ws, size_t ws_size,
                              hipStream_t stream) {
    const float* x  = (const float*)d_in[0];   // [256,512,1024]
    const float* W1 = (const float*)d_in[1];   // [1056,2048]
    const float* b1 = (const float*)d_in[2];   // [2048]
    const float* W2 = (const float*)d_in[3];   // [2048,32]
    const float* b2 = (const float*)d_in[4];   // [32]

    const size_t G_BYTES = (size_t)BATCH * SEQ * HID * sizeof(float);   // 1 GiB
    const size_t A_BYTES = (size_t)BATCH * SEQ * DIM * sizeof(ushort);  // 256 MiB
    const size_t B_BYTES = (size_t)HID * DIM * sizeof(ushort);          // 4 MiB

    float* G = (float*)d_ws;
    float* out_logits = (float*)d_out;
    float* out_preds  = (float*)d_out + (size_t)BATCH * SEQ * NOUT;

    const size_t need_new = G_BYTES + 2 * A_BYTES + 2 * B_BYTES;

    if (ws_size >= need_new) {
        ushort* Ah = (ushort*)((char*)d_ws + G_BYTES);
        ushort* Al = (ushort*)((char*)Ah + A_BYTES);
        ushort* Bh = (ushort*)((char*)Al + A_BYTES);
        ushort* Bl = (ushort*)((char*)Bh + B_BYTES);

        prep_a<<<dim3(TM_TILES, KT_PER_SEG), 256, 0, stream>>>(x, Ah, Al);
        prep_b<<<dim3(TN_TILES, KT_PER_SEG), 256, 0, stream>>>(W1, Bh, Bl);
        gemm256<<<dim3(TM_TILES * TN_TILES), 512, 0, stream>>>(Ah, Al, Bh, Bl, b1, G);
    } else {
        // fallback: previous proven path (fits in G + 16 MiB)
        ushort* Bth = (ushort*)((char*)d_ws + G_BYTES);
        ushort* Btl = Bth + (size_t)HID * DIM;
        split_w1t<<<dim3(HID / 32, DIM / 32), 256, 0, stream>>>(W1, Bth, Btl);
        gemm_split<<<dim3(HID / 128, BATCH * SEQ / 128), 256, 0, stream>>>(x, Bth, Btl, b1, G);
    }

    seq_scan<<<BATCH, 1024, 0, stream>>>(G, W1, W2, b2, out_logits, out_preds);
}